// Round 4
// baseline (85.324 us; speedup 1.0000x reference)
//
#include <hip/hip_runtime.h>
#include <math.h>

typedef unsigned int u32;
typedef unsigned long long u64;

#define BB 256
#define CC 28
#define DD 2048
#define KK 16
#define GA 14                    // max anchors/class: minority => m <= 14
#define NBLK (CC * GA)

// ws layout (~5.6 KB of the 256 MiB scratch)
struct Meta {
  float acc[2];                  // Sum NN*dp, Sum NP*dn  (zeroed by k_sel)
  u32 ticket;                    // last-block-done counter (zeroed by k_sel)
  u32 pad;
  int active[CC];
  int mcount[CC];
  int alist[CC][16];             // positives in row order (anchor per slot)
  int slist[CC][16];             // positives sorted asc by prob (tie: smaller row)
  int nlist[CC][16];             // top-16 negatives desc by prob (tie: smaller row)
};

// ---------------------------------------------------------------------------
// k_sel: one block per class. Thread t owns row t. Counts via ballot,
// minority via the stable-argsort cumsum rule, and top-K selection via
// fully parallel rank computation (no sequential extraction): rank of a
// key = #keys of the same category ordered before it; ranks are a
// permutation (row index breaks ties), so scattering key->slot[rank]
// reproduces jax.lax.top_k exactly.
// ---------------------------------------------------------------------------
__global__ __launch_bounds__(256) void k_sel(const float* __restrict__ inp,
                                             const int* __restrict__ target,
                                             Meta* __restrict__ M) {
  const int c = blockIdx.x;
  const int t = threadIdx.x;     // row
  const int wave = t >> 6, lane = t & 63;

  __shared__ u32 s_bits[BB];     // inp[t][c] bits
  __shared__ u32 s_pb[BB];       // row -> 28-bit positive mask
  __shared__ int s_cw[4][CC];
  __shared__ int s_counts[CC];
  __shared__ int s_pw[4];

  // target row bitmask (coalesced int4)
  u32 pb = 0;
  const int4* t4 = (const int4*)(target + t * CC);
#pragma unroll
  for (int k = 0; k < 7; ++k) {
    int4 w = t4[k];
    pb |= (u32)(w.x != 0) << (4 * k) | (u32)(w.y != 0) << (4 * k + 1) |
          (u32)(w.z != 0) << (4 * k + 2) | (u32)(w.w != 0) << (4 * k + 3);
  }
  s_pb[t] = pb;
  const float v = inp[t * CC + c];
  s_bits[t] = __float_as_uint(v);

  // per-class counts via ballot
#pragma unroll
  for (int c2 = 0; c2 < CC; ++c2) {
    u64 b = __ballot((pb >> c2) & 1u);
    if (lane == 0) s_cw[wave][c2] = __popcll(b);
  }
  const int p = (pb >> c) & 1;
  const u64 bp = __ballot(p != 0);
  if (lane == 0) s_pw[wave] = __popcll(bp);
  __syncthreads();
  if (t < CC)
    s_counts[t] = s_cw[0][t] + s_cw[1][t] + s_cw[2][t] + s_cw[3][t];
  __syncthreads();

  const int m = s_counts[c];
  int cum = 0;
#pragma unroll
  for (int c2 = 0; c2 < CC; ++c2) {
    const int m2 = s_counts[c2];
    cum += (m2 < m || (m2 == m && c2 <= c)) ? m2 : 0;
  }
  const bool active = (2 * cum <= CC) && (m > 1);

  if (c == 0 && t == 0) { M->acc[0] = 0.f; M->acc[1] = 0.f; M->ticket = 0u; }
  if (t == 0) { M->active[c] = active ? 1 : 0; M->mcount[c] = m; }
  if (!active) return;           // block-uniform

  // parallel rank among own category
  int rank = 0;
  for (int j = 0; j < BB; ++j) {
    const float vj = __uint_as_float(s_bits[j]);
    const int pj = (s_pb[j] >> c) & 1;
    const bool bpos = (vj < v) || (vj == v && j < t);  // asc order (positives)
    const bool bneg = (vj > v) || (vj == v && j < t);  // desc order (negatives)
    rank += p ? ((pj && bpos) ? 1 : 0) : ((!pj && bneg) ? 1 : 0);
  }
  if (p) {
    if (rank < 16) M->slist[c][rank] = t;  // m <= 14: all positives land
    // anchor slot = #positives with smaller row index
    int idx = __popcll(bp & ((1ull << lane) - 1ull));
#pragma unroll
    for (int w2 = 0; w2 < 4; ++w2)
      if (w2 < wave) idx += s_pw[w2];
    if (idx < 16) M->alist[c][idx] = t;
  } else {
    if (rank < KK) M->nlist[c][rank] = t;
  }
}

// ---------------------------------------------------------------------------
// k_dist: block (c, a) = class c, anchor-slot a. Active blocks compute the
// anchor's weighted L1 distance sums and atomically accumulate; the last
// block to finish (ticket) applies margin + relu and writes out.
// ---------------------------------------------------------------------------
__global__ __launch_bounds__(256) void k_dist(const float* __restrict__ X,
                                              Meta* __restrict__ M,
                                              float* __restrict__ out) {
  const int c = blockIdx.x;
  const int a = blockIdx.y;
  const int tid = threadIdx.x;
  const int wave = tid >> 6, lane = tid & 63;

  __shared__ int s_S[16], s_N[16];
  __shared__ float s_red[8];

  const int m = M->mcount[c];
  const bool work = (M->active[c] != 0) && (a < m);

  if (work) {                    // block-uniform
    if (tid < KK) s_N[tid] = M->nlist[c][tid];
    else if (tid >= 64 && tid < 64 + m) s_S[tid - 64] = M->slist[c][tid - 64];
    __syncthreads();

    const int anchor = M->alist[c][a];
    const int NP = m - 1;              // min(K, m-1), m <= 14
    const int NN = min(KK, BB - m);    // = 16
    int idx_a = 0;
    for (int u = 0; u < m; ++u)
      if (s_S[u] == anchor) idx_a = u;

    // anchor row in registers, coalesced float4
    const float4* Xa = (const float4*)(X + (size_t)anchor * DD);
    float4 A[8];
#pragma unroll
    for (int q = 0; q < 8; ++q) A[q] = Xa[q * 64 + lane];

    float dp = 0.f, dn = 0.f;
    for (int pidx = wave; pidx < NP + NN; pidx += 4) {
      const bool isdp = pidx < NP;
      const int j = isdp ? s_S[pidx + (pidx >= idx_a ? 1 : 0)] : s_N[pidx - NP];
      const float4* Xj = (const float4*)(X + (size_t)j * DD);
      float partial = 0.f;
#pragma unroll
      for (int q = 0; q < 8; ++q) {
        const float4 b4 = Xj[q * 64 + lane];
        partial += fabsf(A[q].x - b4.x) + fabsf(A[q].y - b4.y) +
                   fabsf(A[q].z - b4.z) + fabsf(A[q].w - b4.w);
      }
#pragma unroll
      for (int s = 1; s < 64; s <<= 1) partial += __shfl_xor(partial, s);
      if (isdp) dp += partial; else dn += partial;
    }
    if (lane == 0) { s_red[2 * wave] = dp; s_red[2 * wave + 1] = dn; }
    __syncthreads();
    if (tid == 0) {
      const float dpT = s_red[0] + s_red[2] + s_red[4] + s_red[6];
      const float dnT = s_red[1] + s_red[3] + s_red[5] + s_red[7];
      atomicAdd(&M->acc[0], (float)NN * dpT);
      atomicAdd(&M->acc[1], (float)NP * dnT);
    }
  }

  // last-block-done final (ticket zeroed by k_sel each call)
  if (tid == 0) {
    __threadfence();
    const u32 tk = atomicAdd(&M->ticket, 1u);
    if (tk == (u32)(NBLK - 1)) {
      __threadfence();
      const float a0 = atomicAdd(&M->acc[0], 0.f);  // coherent read
      const float a1 = atomicAdd(&M->acc[1], 0.f);
      out[0] = fmaxf(a0 - a1 + 1.0f, 0.0f);
    }
  }
}

extern "C" void kernel_launch(void* const* d_in, const int* in_sizes, int n_in,
                              void* d_out, int out_size, void* d_ws, size_t ws_size,
                              hipStream_t stream) {
  (void)in_sizes; (void)n_in; (void)out_size; (void)ws_size;
  const float* inp    = (const float*)d_in[0];  // [256,28] f32
  const int*   target = (const int*)d_in[1];    // [256,28] i32
  const float* X      = (const float*)d_in[2];  // [256,2048] f32
  float* out = (float*)d_out;
  Meta* M = (Meta*)d_ws;

  k_sel<<<CC, 256, 0, stream>>>(inp, target, M);
  k_dist<<<dim3(CC, GA), 256, 0, stream>>>(X, M, out);
}

// Round 6
// 81.084 us; speedup vs baseline: 1.0523x; 1.0523x over previous
//
#include <hip/hip_runtime.h>
#include <math.h>

typedef unsigned int u32;
typedef unsigned long long u64;

#define BB 256
#define CC 28
#define DD 2048
#define KK 16
#define GA 14                    // max anchors/class: minority => m <= 14

// ws layout (~6 KB of scratch)
struct Meta {
  int active[CC];
  int mcount[CC];
  int alist[CC][16];             // positives in row order (anchor per slot)
  int slist[CC][16];             // positives sorted asc by prob (tie: smaller row)
  int nlist[CC][16];             // top-16 negatives desc by prob (tie: smaller row)
};

// ---------------------------------------------------------------------------
// k_sel: one block per class. Thread t owns row t. Counts via ballot,
// minority via the stable-argsort cumsum rule, top-K selection via fully
// parallel rank computation (rank = #keys of same category ordered before
// me; ranks are a permutation since row index breaks ties) — reproduces
// jax.lax.top_k stable tie-breaking exactly (verified: absmax 0 in R4).
// ---------------------------------------------------------------------------
__global__ __launch_bounds__(256) void k_sel(const float* __restrict__ inp,
                                             const int* __restrict__ target,
                                             Meta* __restrict__ M) {
  const int c = blockIdx.x;
  const int t = threadIdx.x;     // row
  const int wave = t >> 6, lane = t & 63;

  __shared__ u32 s_bits[BB];     // inp[t][c] bits
  __shared__ u32 s_pb[BB];       // row -> 28-bit positive mask
  __shared__ int s_cw[4][CC];
  __shared__ int s_counts[CC];
  __shared__ int s_pw[4];

  // target row bitmask (coalesced int4)
  u32 pb = 0;
  const int4* t4 = (const int4*)(target + t * CC);
#pragma unroll
  for (int k = 0; k < 7; ++k) {
    int4 w = t4[k];
    pb |= (u32)(w.x != 0) << (4 * k) | (u32)(w.y != 0) << (4 * k + 1) |
          (u32)(w.z != 0) << (4 * k + 2) | (u32)(w.w != 0) << (4 * k + 3);
  }
  s_pb[t] = pb;
  const float v = inp[t * CC + c];
  s_bits[t] = __float_as_uint(v);

  // per-class counts via ballot
#pragma unroll
  for (int c2 = 0; c2 < CC; ++c2) {
    u64 b = __ballot((pb >> c2) & 1u);
    if (lane == 0) s_cw[wave][c2] = __popcll(b);
  }
  const int p = (pb >> c) & 1;
  const u64 bp = __ballot(p != 0);
  if (lane == 0) s_pw[wave] = __popcll(bp);
  __syncthreads();
  if (t < CC)
    s_counts[t] = s_cw[0][t] + s_cw[1][t] + s_cw[2][t] + s_cw[3][t];
  __syncthreads();

  const int m = s_counts[c];
  int cum = 0;
#pragma unroll
  for (int c2 = 0; c2 < CC; ++c2) {
    const int m2 = s_counts[c2];
    cum += (m2 < m || (m2 == m && c2 <= c)) ? m2 : 0;
  }
  const bool active = (2 * cum <= CC) && (m > 1);

  if (t == 0) { M->active[c] = active ? 1 : 0; M->mcount[c] = m; }
  if (!active) return;           // block-uniform

  // parallel rank among own category (asc for positives, desc for negatives)
  int rank = 0;
  for (int j = 0; j < BB; ++j) {
    const float vj = __uint_as_float(s_bits[j]);
    const int pj = (s_pb[j] >> c) & 1;
    const bool bpos = (vj < v) || (vj == v && j < t);
    const bool bneg = (vj > v) || (vj == v && j < t);
    rank += p ? ((pj && bpos) ? 1 : 0) : ((!pj && bneg) ? 1 : 0);
  }
  if (p) {
    if (rank < 16) M->slist[c][rank] = t;  // m <= 14: all positives land
    // anchor slot = #positives with smaller row index
    int idx = __popcll(bp & ((1ull << lane) - 1ull));
#pragma unroll
    for (int w2 = 0; w2 < 4; ++w2)
      if (w2 < wave) idx += s_pw[w2];
    if (idx < 16) M->alist[c][idx] = t;
  } else {
    if (rank < KK) M->nlist[c][rank] = t;
  }
}

// ---------------------------------------------------------------------------
// k_dist: block (c, a) = class c, anchor-slot a. Active blocks compute the
// anchor's weighted L1 distance sums; EVERY block writes its private slot
// in part[] (no atomics, no fences, deterministic; ws is poisoned so
// inactive blocks must write zeros).
// ---------------------------------------------------------------------------
__global__ __launch_bounds__(256) void k_dist(const float* __restrict__ X,
                                              const Meta* __restrict__ M,
                                              float* __restrict__ part) {
  const int c = blockIdx.x;
  const int a = blockIdx.y;
  const int tid = threadIdx.x;
  const int wave = tid >> 6, lane = tid & 63;

  __shared__ int s_S[16], s_N[16];
  __shared__ float s_red[8];

  const int m = M->mcount[c];
  const bool work = (M->active[c] != 0) && (a < m);

  float outp = 0.f, outn = 0.f;
  if (work) {                    // block-uniform
    if (tid < KK) s_N[tid] = M->nlist[c][tid];
    else if (tid >= 64 && tid < 64 + m) s_S[tid - 64] = M->slist[c][tid - 64];
    __syncthreads();

    const int anchor = M->alist[c][a];
    const int NP = m - 1;              // = min(K, m-1) since m <= 14
    const int NN = min(KK, BB - m);    // = 16
    int idx_a = 0;
    for (int u = 0; u < m; ++u)
      if (s_S[u] == anchor) idx_a = u;

    // anchor row in registers, coalesced float4
    const float4* Xa = (const float4*)(X + (size_t)anchor * DD);
    float4 A[8];
#pragma unroll
    for (int q = 0; q < 8; ++q) A[q] = Xa[q * 64 + lane];

    float dp = 0.f, dn = 0.f;
    for (int pidx = wave; pidx < NP + NN; pidx += 4) {
      const bool isdp = pidx < NP;
      const int j = isdp ? s_S[pidx + (pidx >= idx_a ? 1 : 0)] : s_N[pidx - NP];
      const float4* Xj = (const float4*)(X + (size_t)j * DD);
      float partial = 0.f;
#pragma unroll
      for (int q = 0; q < 8; ++q) {
        const float4 b4 = Xj[q * 64 + lane];
        partial += fabsf(A[q].x - b4.x) + fabsf(A[q].y - b4.y) +
                   fabsf(A[q].z - b4.z) + fabsf(A[q].w - b4.w);
      }
#pragma unroll
      for (int s = 1; s < 64; s <<= 1) partial += __shfl_xor(partial, s);
      if (isdp) dp += partial; else dn += partial;
    }
    if (lane == 0) { s_red[2 * wave] = dp; s_red[2 * wave + 1] = dn; }
    __syncthreads();
    outp = (float)NN * (s_red[0] + s_red[2] + s_red[4] + s_red[6]);
    outn = (float)NP * (s_red[1] + s_red[3] + s_red[5] + s_red[7]);
  }

  if (tid == 0) {
    part[2 * (c * GA + a)]     = outp;
    part[2 * (c * GA + a) + 1] = outn;
  }
}

// ---------------------------------------------------------------------------
// k_final: sum the 392 partial pairs, apply margin + relu.
// ---------------------------------------------------------------------------
__global__ __launch_bounds__(256) void k_final(const float* __restrict__ part,
                                               float* __restrict__ out) {
  const int tid = threadIdx.x;
  const int wave = tid >> 6, lane = tid & 63;
  __shared__ float s_red[8];

  float dp = 0.f, dn = 0.f;
  for (int t = tid; t < CC * GA; t += 256) {
    dp += part[2 * t];
    dn += part[2 * t + 1];
  }
#pragma unroll
  for (int s = 1; s < 64; s <<= 1) {
    dp += __shfl_xor(dp, s);
    dn += __shfl_xor(dn, s);
  }
  if (lane == 0) { s_red[2 * wave] = dp; s_red[2 * wave + 1] = dn; }
  __syncthreads();
  if (tid == 0) {
    const float dpT = s_red[0] + s_red[2] + s_red[4] + s_red[6];
    const float dnT = s_red[1] + s_red[3] + s_red[5] + s_red[7];
    out[0] = fmaxf(dpT - dnT + 1.0f, 0.0f);
  }
}

extern "C" void kernel_launch(void* const* d_in, const int* in_sizes, int n_in,
                              void* d_out, int out_size, void* d_ws, size_t ws_size,
                              hipStream_t stream) {
  (void)in_sizes; (void)n_in; (void)out_size; (void)ws_size;
  const float* inp    = (const float*)d_in[0];  // [256,28] f32
  const int*   target = (const int*)d_in[1];    // [256,28] i32
  const float* X      = (const float*)d_in[2];  // [256,2048] f32
  float* out = (float*)d_out;

  Meta*  M    = (Meta*)d_ws;
  float* part = (float*)((char*)d_ws + sizeof(Meta));  // [392][2]

  k_sel<<<CC, 256, 0, stream>>>(inp, target, M);
  k_dist<<<dim3(CC, GA), 256, 0, stream>>>(X, M, part);
  k_final<<<1, 256, 0, stream>>>(part, out);
}